// Round 8
// baseline (681.524 us; speedup 1.0000x reference)
//
#include <hip/hip_runtime.h>

#define L2E 1.4426950408889634f

typedef _Float16 f16x8 __attribute__((ext_vector_type(8)));
typedef _Float16 f16x4 __attribute__((ext_vector_type(4)));
typedef float f32x4 __attribute__((ext_vector_type(4)));

__device__ __forceinline__ float sig_fast(float x) {
    return __builtin_amdgcn_rcpf(1.0f + __builtin_amdgcn_exp2f(-L2E * x));
}
__device__ __forceinline__ float tanh_fast(float x) {
    return 1.0f - 2.0f * __builtin_amdgcn_rcpf(1.0f + __builtin_amdgcn_exp2f(2.0f * L2E * x));
}
__device__ __forceinline__ float expnr_fast(float x) {  // exp(-relu(x))
    return __builtin_amdgcn_exp2f(-L2E * fmaxf(x, 0.0f));
}
// Orders LDS only; global loads/stores stay in flight across the barrier.
__device__ __forceinline__ void barrier_lds_only() {
    __asm__ volatile("s_waitcnt lgkmcnt(0)\n\ts_barrier" ::: "memory");
}

struct F8 { float v[8]; };
__device__ __forceinline__ F8 ld8(const float* p) {
    F8 r;
    float4 a = *(const float4*)p, b = *(const float4*)(p + 4);
    r.v[0]=a.x; r.v[1]=a.y; r.v[2]=a.z; r.v[3]=a.w;
    r.v[4]=b.x; r.v[5]=b.y; r.v[6]=b.z; r.v[7]=b.w;
    return r;
}
__device__ __forceinline__ f16x8 cvt8(F8 a) {
    f16x8 r;
#pragma unroll
    for (int q = 0; q < 8; ++q) r[q] = (_Float16)a.v[q];
    return r;
}
__device__ __forceinline__ f16x8 cvt8s(F8 a, F8 b) {
    f16x8 r;
#pragma unroll
    for (int q = 0; q < 8; ++q) r[q] = (_Float16)(a.v[q] + b.v[q]);
    return r;
}

// 512 blocks x 2 batch rows, 768 threads = 12 waves, TWO blocks co-resident
// per CU (the R7 lesson: barrier-locked waves inside a block cannot pipeline
// across the per-step barrier, so overlap must come from an INDEPENDENT
// block on the same CU). __launch_bounds__(768,6) pins VGPR<=85 so
// 2x12 waves fit (24/CU, 6/SIMD).
//   waves 0-7 (consumers): serial GRU recurrence, h-part GEMM (K=128);
//     wave w owns 16 hidden cols; batches live at tile rows {0,4} (quad 0,1).
//   waves 8-11 (producers): x/m-part GEMM one granule (4 steps x 2 batches =
//     8 A-rows) ahead into an 8-slot LDS ring + tail projection + mu.
__global__ __launch_bounds__(768, 6) void grud_kernel(
    const float* __restrict__ tp_pred, const float* __restrict__ X,
    const float* __restrict__ tp_true, const float* __restrict__ mask,
    const float* __restrict__ Wh_dec, const float* __restrict__ bh_dec,
    const float* __restrict__ Wx_dec, const float* __restrict__ bx_dec,
    const float* __restrict__ W_ih, const float* __restrict__ W_hh,
    const float* __restrict__ b_ih, const float* __restrict__ b_hh,
    const float* __restrict__ Wp, const float* __restrict__ bp,
    float* __restrict__ out)
{
    constexpr int SR = 136;   // A-tile row stride (halfs): 128 + 8 pad
    constexpr int RS = 1032;  // ring slot stride (halfs): 2*128*4 + 8 skew
    __shared__ alignas(16) _Float16 ring[8 * RS];    // [slot][b][c][{r,z,n,pad}] 16.5KB
    __shared__ alignas(16) _Float16 V[2][16 * SR];   // h A-tiles (rows {0,4} live)
    __shared__ alignas(16) _Float16 Astage[16 * SR]; // x_in/m A-tile (rows 0-7 live)
    __shared__ float dt_lds[240];                    // [t][b]
    __shared__ float mu_l[2][64];
    __shared__ float wxl[64], bxl[64];

    const int tid  = threadIdx.x;
    const int w    = tid >> 6, l = tid & 63, quad = l >> 4, lm = l & 15;
    const int b0   = blockIdx.x * 2;

    // zero V (both buffers) and Astage: dead tile rows must stay 0 forever
    for (int i = tid; i < 16 * SR; i += 768) ((unsigned*)V)[i] = 0;       // = 2x16xSR halfs
    for (int i = tid; i < 8 * SR; i += 768) ((unsigned*)Astage)[i] = 0;   // = 16xSR halfs

    // dt: [t][b], 120 x 2
    if (tid < 240) {
        int t = tid >> 1, b = b0 + (tid & 1);
        float v = 0.0f;
        if (t) {
            float cur = (t < 96) ? tp_true[b * 96 + t] : tp_pred[b * 24 + t - 96];
            float prv = (t - 1 < 96) ? tp_true[b * 96 + t - 1] : tp_pred[b * 24 + t - 97];
            v = cur - prv;
        }
        dt_lds[tid] = v;
    }
    if (tid < 64) { wxl[tid] = Wx_dec[tid * 65]; bxl[tid] = bx_dec[tid]; }

    if (w >= 8) {
        // ===================== PRODUCER WAVES (8..11) =====================
        const int pw   = w - 8;          // 0..3
        const int ptid = tid - 512;      // 0..255
        const int c0   = 32 * pw + lm, c1 = c0 + 16;

        // mu: waves 8,9 -> batch pw (lane l -> feature l)
        if (pw < 2) {
            const float* xr = X    + ((size_t)(b0 + pw) * 96) * 64 + l;
            const float* mr = mask + ((size_t)(b0 + pw) * 96) * 64 + l;
            float a = 0.0f, c = 0.0f;
#pragma unroll 4
            for (int t = 0; t < 96; ++t) {
                float x = xr[t * 64], m = mr[t * 64];
                a += x * (1.0f - m); c += 1.0f - m;
            }
            mu_l[pw][l] = a / (c + 24.0f);  // cnt = sum(1-m) + 24 >= 24, no clip
        }

        // x/m-part B-frags: k<64 -> W_ih[:, :64]; k>=64 -> W_ih[:, 192:]
        f16x8 wxf[3][2][4];
#pragma unroll
        for (int g = 0; g < 3; ++g)
#pragma unroll
            for (int j = 0; j < 2; ++j)
#pragma unroll
                for (int fi = 0; fi < 4; ++fi) {
                    const int row = g * 128 + (j ? c1 : c0);
                    const int k0 = fi * 32 + quad * 8;
                    wxf[g][j][fi] = cvt8(ld8(W_ih + row * 256 + (k0 < 64 ? k0 : 128 + k0)));
                }

        // projection weights (wave covers out cols pn)
        const int pn = pw * 16 + lm;
        const float bpv = bp[pn];
        f16x8 wPf[4];
#pragma unroll
        for (int fi = 0; fi < 4; ++fi)
            wPf[fi] = cvt8(ld8(Wp + pn * 128 + fi * 32 + quad * 8));

        // granule gp = 4 timesteps x 2 batches staged in A-rows R = 2*toff+b (R<8)
        auto prodLoad = [&](int gp, float4& px, float4& pm) {
            px = make_float4(0,0,0,0); pm = make_float4(0,0,0,0);
            const int R = ptid >> 4;
            if (gp >= 24 || R >= 8) return;
            const int tg = 4 * gp + (R >> 1), b = R & 1;
            const size_t o = (((size_t)(b0 + b) * 96) + tg) * 64 + (ptid & 15) * 4;
            px = *(const float4*)(X + o);
            pm = *(const float4*)(mask + o);
        };
        auto prodStage = [&](int gp, float4 px, float4 pm) {
            const int R = ptid >> 4;
            if (R >= 8) return;
            const int toff = R >> 1, b = R & 1;
            const int tg = 4 * gp + toff, n0 = (ptid & 15) * 4;
            const float d = dt_lds[tg * 2 + b];
            const float xs[4] = {px.x, px.y, px.z, px.w};
            const float ms[4] = {pm.x, pm.y, pm.z, pm.w};
            f16x4 xi, mm;
#pragma unroll
            for (int e = 0; e < 4; ++e) {
                const int n = n0 + e;
                const float gxv = expnr_fast(d * wxl[n] + bxl[n]);
                const float muv = mu_l[b][n];
                float v;
                if (gp < 24) {  // LOCF collapse: m==0 -> X_locf == x_t
                    v = (ms[e] != 0.0f) ? xs[e] : (xs[e] - muv) * gxv + muv;
                    mm[e] = (_Float16)ms[e];
                } else {        // t>=96: x=0,m=0 -> x_in = (1-gx)*mu
                    v = (1.0f - gxv) * muv;
                    mm[e] = (_Float16)0.0f;
                }
                xi[e] = (_Float16)v;
            }
            *(f16x4*)&Astage[R * SR + n0]      = xi;
            *(f16x4*)&Astage[R * SR + 64 + n0] = mm;
        };
        auto prodMMA = [&](int gp, int j) {
            f16x8 ap[4];
#pragma unroll
            for (int fi = 0; fi < 4; ++fi)
                ap[fi] = *(const f16x8*)&Astage[lm * SR + fi * 32 + quad * 8];
            const int c = j ? c1 : c0;
            f32x4 aR = {0,0,0,0}, aZ = {0,0,0,0}, aN = {0,0,0,0};
#pragma unroll
            for (int fi = 0; fi < 4; ++fi) {
                aR = __builtin_amdgcn_mfma_f32_16x16x32_f16(ap[fi], wxf[0][j][fi], aR, 0, 0, 0);
                aZ = __builtin_amdgcn_mfma_f32_16x16x32_f16(ap[fi], wxf[1][j][fi], aZ, 0, 0, 0);
                aN = __builtin_amdgcn_mfma_f32_16x16x32_f16(ap[fi], wxf[2][j][fi], aN, 0, 0, 0);
            }
            // C/D row 4*quad+rb = staged row R -> timestep 4gp+2quad+(rb>>1), batch rb&1.
            // Only quads 0,1 carry real rows (R<8); quads 2,3 must not write
            // (their slots would alias the NEXT granule).
            if (quad < 2) {
#pragma unroll
                for (int rb = 0; rb < 4; ++rb) {
                    const int slot = (4 * gp + 2 * quad + (rb >> 1)) & 7;
                    const int b = rb & 1;
                    f16x4 pk = {(_Float16)aR[rb], (_Float16)aZ[rb], (_Float16)aN[rb], (_Float16)0.0f};
                    *(f16x4*)&ring[slot * RS + ((b << 7) + c) * 4] = pk;
                }
            }
        };

        __syncthreads();      // #1: mu/dt/wxl/zeros visible
        {   // preamble: granule 0 (ring slots 0-3); barrier between stage & MMA
            float4 px, pm;
            prodLoad(0, px, pm);
            prodStage(0, px, pm);
            barrier_lds_only();   // #2: Astage staged (cross-wave) before read
            prodMMA(0, 0); prodMMA(0, 1);
            barrier_lds_only();   // #3: granule 0 visible to consumers
        }

        float4 px, pm;
        for (int t = 0; t < 120; ++t) {
            const int gp = (t >> 2) + 1, ph = t & 3;
            if (ph == 0)      { if (gp < 30) prodLoad(gp, px, pm); }
            else if (ph == 1) { if (gp < 30) prodStage(gp, px, pm); }
            else if (ph == 2) { if (gp < 30) prodMMA(gp, 0); }
            else              { if (gp < 30) prodMMA(gp, 1); }

            if (t >= 96) {  // projection: rep_t = decayed h = V[t&1] tile
                f16x8 af[4];
#pragma unroll
                for (int fi = 0; fi < 4; ++fi)
                    af[fi] = *(const f16x8*)&V[t & 1][lm * SR + fi * 32 + quad * 8];
                f32x4 aP = {bpv, 0, 0, 0};
#pragma unroll
                for (int fi = 0; fi < 4; ++fi)
                    aP = __builtin_amdgcn_mfma_f32_16x16x32_f16(af[fi], wPf[fi], aP, 0, 0, 0);
                if (quad < 2)
                    out[((size_t)(b0 + quad) * 24 + (t - 96)) * 64 + pn] = aP[0];
            }
            barrier_lds_only();
        }
    } else {
        // ===================== CONSUMER WAVES (0..7) =====================
        const int c = 16 * w + lm;  // this lane's single hidden col

        // h-part B-frags (W_ih cols 64..191; +W_hh folded for r,z): 64 VGPR
        f16x8 wR[4], wZ[4], wN[4], wG[4];
#pragma unroll
        for (int fi = 0; fi < 4; ++fi) {
            const int k0 = fi * 32 + quad * 8;
            wR[fi] = cvt8s(ld8(W_ih + c * 256 + 64 + k0),
                           ld8(W_hh + c * 128 + k0));
            wZ[fi] = cvt8s(ld8(W_ih + (128 + c) * 256 + 64 + k0),
                           ld8(W_hh + (128 + c) * 128 + k0));
            wN[fi] = cvt8(ld8(W_ih + (256 + c) * 256 + 64 + k0));
            wG[fi] = cvt8(ld8(W_hh + (256 + c) * 128 + k0));
        }
        float S = 0.0f;
        {
            const float4* wh4 = (const float4*)(Wh_dec + c * 64);
#pragma unroll
            for (int i = 0; i < 16; ++i) { float4 u = wh4[i]; S += u.x + u.y + u.z + u.w; }
        }
        const float bhc = bh_dec[c];
        const float bRc = b_ih[c] + b_hh[c];
        const float bZc = b_ih[128 + c] + b_hh[128 + c];
        const float bNc = b_ih[256 + c];
        const float bGc = b_hh[256 + c];

        __syncthreads();      // #1 (pairs with producer's)
        barrier_lds_only();   // #2
        barrier_lds_only();   // #3

        const f32x4 ZV = {0.0f, 0.0f, 0.0f, 0.0f};
        const int bq = quad & 1;  // quads 2,3 mirror 0,1 (same-addr broadcast; h unused)
        float h = 0.0f;
        for (int t = 0; t < 120; ++t) {
            const _Float16* Vp = V[t & 1];
            const f16x4 g = *(const f16x4*)&ring[(t & 7) * RS + ((bq << 7) + c) * 4];
            f16x8 af[4];
#pragma unroll
            for (int fi = 0; fi < 4; ++fi)
                af[fi] = *(const f16x8*)&Vp[lm * SR + fi * 32 + quad * 8];

            // gh for t+1, off the gate chain
            const int tn = (t < 119) ? t + 1 : 119;
            const float ghd = expnr_fast(dt_lds[tn * 2 + bq] * S + bhc);

            f32x4 aR = __builtin_amdgcn_mfma_f32_16x16x32_f16(af[0], wR[0], ZV, 0, 0, 0);
            f32x4 aZ = __builtin_amdgcn_mfma_f32_16x16x32_f16(af[0], wZ[0], ZV, 0, 0, 0);
            f32x4 aN = __builtin_amdgcn_mfma_f32_16x16x32_f16(af[0], wN[0], ZV, 0, 0, 0);
            f32x4 aG = __builtin_amdgcn_mfma_f32_16x16x32_f16(af[0], wG[0], ZV, 0, 0, 0);
#pragma unroll
            for (int fi = 1; fi < 4; ++fi) {
                aR = __builtin_amdgcn_mfma_f32_16x16x32_f16(af[fi], wR[fi], aR, 0, 0, 0);
                aZ = __builtin_amdgcn_mfma_f32_16x16x32_f16(af[fi], wZ[fi], aZ, 0, 0, 0);
                aN = __builtin_amdgcn_mfma_f32_16x16x32_f16(af[fi], wN[fi], aN, 0, 0, 0);
                aG = __builtin_amdgcn_mfma_f32_16x16x32_f16(af[fi], wG[fi], aG, 0, 0, 0);
            }

            // gate triple (C/D reg 0: tile row 4*quad -> batch quad for quad<2)
            const float rg = sig_fast(aR[0] + ((float)g[0] + bRc));
            const float zg = sig_fast(aZ[0] + ((float)g[1] + bZc));
            const float ng = tanh_fast(aN[0] + ((float)g[2] + bNc) + rg * (aG[0] + bGc));
            h = (zg * (h - ng) + ng) * ghd;   // decayed h = rep_{t+1}
            if (t < 119 && quad < 2)
                V[(t & 1) ^ 1][(4 * quad) * SR + c] = (_Float16)h;
            barrier_lds_only();
        }
    }
}

extern "C" void kernel_launch(void* const* d_in, const int* in_sizes, int n_in,
                              void* d_out, int out_size, void* d_ws, size_t ws_size,
                              hipStream_t stream) {
    const float* tp_pred = (const float*)d_in[0];
    const float* X       = (const float*)d_in[1];
    const float* tp_true = (const float*)d_in[2];
    const float* mask    = (const float*)d_in[3];
    const float* Wh_dec  = (const float*)d_in[4];
    const float* bh_dec  = (const float*)d_in[5];
    const float* Wx_dec  = (const float*)d_in[6];
    const float* bx_dec  = (const float*)d_in[7];
    const float* W_ih    = (const float*)d_in[8];
    const float* W_hh    = (const float*)d_in[9];
    const float* b_ih    = (const float*)d_in[10];
    const float* b_hh    = (const float*)d_in[11];
    const float* Wp      = (const float*)d_in[12];
    const float* bp      = (const float*)d_in[13];

    grud_kernel<<<dim3(512), dim3(768), 0, stream>>>(
        tp_pred, X, tp_true, mask, Wh_dec, bh_dec, Wx_dec, bx_dec,
        W_ih, W_hh, b_ih, b_hh, Wp, bp, (float*)d_out);
}

// Round 9
// 198.984 us; speedup vs baseline: 3.4250x; 3.4250x over previous
//
#include <hip/hip_runtime.h>

#define L2E 1.4426950408889634f

typedef _Float16 f16x8 __attribute__((ext_vector_type(8)));
typedef _Float16 f16x4 __attribute__((ext_vector_type(4)));
typedef float f32x4 __attribute__((ext_vector_type(4)));

__device__ __forceinline__ float sig_fast(float x) {
    return __builtin_amdgcn_rcpf(1.0f + __builtin_amdgcn_exp2f(-L2E * x));
}
__device__ __forceinline__ float tanh_fast(float x) {
    return 1.0f - 2.0f * __builtin_amdgcn_rcpf(1.0f + __builtin_amdgcn_exp2f(2.0f * L2E * x));
}
__device__ __forceinline__ float expnr_fast(float x) {  // exp(-relu(x))
    return __builtin_amdgcn_exp2f(-L2E * fmaxf(x, 0.0f));
}
// Orders LDS only; global loads/stores stay in flight across the barrier.
__device__ __forceinline__ void barrier_lds_only() {
    __asm__ volatile("s_waitcnt lgkmcnt(0)\n\ts_barrier" ::: "memory");
}

struct F8 { float v[8]; };
__device__ __forceinline__ F8 ld8(const float* p) {
    F8 r;
    float4 a = *(const float4*)p, b = *(const float4*)(p + 4);
    r.v[0]=a.x; r.v[1]=a.y; r.v[2]=a.z; r.v[3]=a.w;
    r.v[4]=b.x; r.v[5]=b.y; r.v[6]=b.z; r.v[7]=b.w;
    return r;
}
__device__ __forceinline__ f16x8 cvt8(F8 a) {
    f16x8 r;
#pragma unroll
    for (int q = 0; q < 8; ++q) r[q] = (_Float16)a.v[q];
    return r;
}
__device__ __forceinline__ f16x8 cvt8s(F8 a, F8 b) {
    f16x8 r;
#pragma unroll
    for (int q = 0; q < 8; ++q) r[q] = (_Float16)(a.v[q] + b.v[q]);
    return r;
}

// 256 blocks x 4 batch rows, 512 threads = 8 waves (R5 shape — best measured):
//   waves 0-3 (consumers): serial GRU recurrence; wave w owns 32 hidden cols.
//   waves 4-7 (producers): x/m-part gate GEMM one granule (4 steps) ahead
//     into an 8-slot ring + tail projection + mu.
// LDS DIET (R9): MFMA D-row m depends only on A-row m, so the A-tile needs
// only the 4 REAL batch rows — V is 4x128 compact; lane lm reads row lm>>2
// (lanes with lm&3!=0 broadcast-read harmless data; their D-rows are never
// consumed). Producer reads Astage ONCE for both col-tiles. Ring laid out
// [slot][b][c] for conflict-free b64. No launch-bounds VGPR cap (R8 lesson:
// capping below the weight footprint spills to scratch -> 1.2 GB HBM).
__global__ __launch_bounds__(512, 2) void grud_kernel(
    const float* __restrict__ tp_pred, const float* __restrict__ X,
    const float* __restrict__ tp_true, const float* __restrict__ mask,
    const float* __restrict__ Wh_dec, const float* __restrict__ bh_dec,
    const float* __restrict__ Wx_dec, const float* __restrict__ bx_dec,
    const float* __restrict__ W_ih, const float* __restrict__ W_hh,
    const float* __restrict__ b_ih, const float* __restrict__ b_hh,
    const float* __restrict__ Wp, const float* __restrict__ bp,
    float* __restrict__ out)
{
    constexpr int VR = 136;   // compact V row stride (halfs): 128 + 8 pad
    constexpr int AR = 136;   // Astage row stride
    constexpr int RS = 2056;  // ring slot stride (halfs): 4*128*4 + 8 skew
    __shared__ alignas(16) _Float16 ring[8 * RS];    // [slot][b][c][{r,z,n,pad}] ~32.9KB
    __shared__ alignas(16) _Float16 V4[2][4 * VR];   // compact h tiles (4 batch rows)
    __shared__ alignas(16) _Float16 Astage[16 * AR]; // x_in|m A-tile (16 real rows)
    __shared__ float dt_lds[480];                    // [t][b]
    __shared__ float mu_l[4][64];
    __shared__ float wxl[64], bxl[64];

    const int tid  = threadIdx.x;
    const int w    = tid >> 6, l = tid & 63, quad = l >> 4, lm = l & 15;
    const int b0   = blockIdx.x * 4;

    // zero V4 (t=0 state: h=0), both buffers = 4*VR uints
    for (int i = tid; i < 4 * VR; i += 512) ((unsigned*)V4)[i] = 0;

    // dt: [t][b]
    if (tid < 480) {
        int t = tid >> 2, b = b0 + (tid & 3);
        float v = 0.0f;
        if (t) {
            float cur = (t < 96) ? tp_true[b * 96 + t] : tp_pred[b * 24 + t - 96];
            float prv = (t - 1 < 96) ? tp_true[b * 96 + t - 1] : tp_pred[b * 24 + t - 97];
            v = cur - prv;
        }
        dt_lds[tid] = v;
    }
    if (tid < 64) { wxl[tid] = Wx_dec[tid * 65]; bxl[tid] = bx_dec[tid]; }

    if (w >= 4) {
        // ===================== PRODUCER WAVES (4..7) =====================
        const int pw   = w - 4;          // 0..3
        const int ptid = tid - 256;      // 0..255
        const int c0   = 32 * pw + lm, c1 = c0 + 16;

        // mu for batch pw (lane l -> feature l)
        {
            const float* xr = X    + ((size_t)(b0 + pw) * 96) * 64 + l;
            const float* mr = mask + ((size_t)(b0 + pw) * 96) * 64 + l;
            float a = 0.0f, c = 0.0f;
#pragma unroll 4
            for (int t = 0; t < 96; ++t) {
                float x = xr[t * 64], m = mr[t * 64];
                a += x * (1.0f - m); c += 1.0f - m;
            }
            mu_l[pw][l] = a / (c + 24.0f);  // cnt = sum(1-m) + 24 >= 24, no clip
        }

        // x/m-part B-frags: k<64 -> W_ih[:, :64]; k>=64 -> W_ih[:, 192:]
        f16x8 wxf[3][2][4];
#pragma unroll
        for (int g = 0; g < 3; ++g)
#pragma unroll
            for (int j = 0; j < 2; ++j)
#pragma unroll
                for (int fi = 0; fi < 4; ++fi) {
                    const int row = g * 128 + (j ? c1 : c0);
                    const int k0 = fi * 32 + quad * 8;
                    wxf[g][j][fi] = cvt8(ld8(W_ih + row * 256 + (k0 < 64 ? k0 : 128 + k0)));
                }

        // projection weights (wave covers out cols pn)
        const int pn = pw * 16 + lm;
        const float bpv = bp[pn];
        f16x8 wPf[4];
#pragma unroll
        for (int fi = 0; fi < 4; ++fi)
            wPf[fi] = cvt8(ld8(Wp + pn * 128 + fi * 32 + quad * 8));

        // granule gp = timesteps 4gp..4gp+3, all 4 batches; A-row R = 4*toff + b
        auto prodLoad = [&](int gp, float4& px, float4& pm) {
            if (gp >= 24) { px = make_float4(0,0,0,0); pm = make_float4(0,0,0,0); return; }
            const int R = ptid >> 4, tg = 4 * gp + (R >> 2), b = R & 3;
            const size_t o = (((size_t)(b0 + b) * 96) + tg) * 64 + (ptid & 15) * 4;
            px = *(const float4*)(X + o);
            pm = *(const float4*)(mask + o);
        };
        auto prodStage = [&](int gp, float4 px, float4 pm) {
            const int R = ptid >> 4, toff = R >> 2, b = R & 3;
            const int tg = 4 * gp + toff, n0 = (ptid & 15) * 4;
            const float d = dt_lds[tg * 4 + b];
            const float xs[4] = {px.x, px.y, px.z, px.w};
            const float ms[4] = {pm.x, pm.y, pm.z, pm.w};
            f16x4 xi, mm;
#pragma unroll
            for (int e = 0; e < 4; ++e) {
                const int n = n0 + e;
                const float gxv = expnr_fast(d * wxl[n] + bxl[n]);
                const float muv = mu_l[b][n];
                float v;
                if (gp < 24) {  // LOCF collapse: m==0 -> X_locf == x_t
                    v = (ms[e] != 0.0f) ? xs[e] : (xs[e] - muv) * gxv + muv;
                    mm[e] = (_Float16)ms[e];
                } else {        // t>=96: x=0,m=0 -> x_in = (1-gx)*mu
                    v = (1.0f - gxv) * muv;
                    mm[e] = (_Float16)0.0f;
                }
                xi[e] = (_Float16)v;
            }
            *(f16x4*)&Astage[R * AR + n0]      = xi;
            *(f16x4*)&Astage[R * AR + 64 + n0] = mm;
        };
        // merged: ONE Astage read feeds both col-tiles (24 MFMAs)
        auto prodMMA = [&](int gp) {
            f16x8 ap[4];
#pragma unroll
            for (int fi = 0; fi < 4; ++fi)
                ap[fi] = *(const f16x8*)&Astage[lm * AR + fi * 32 + quad * 8];
            const int slot = (4 * gp + quad) & 7;  // quad = time offset
            f32x4 aR0 = {0,0,0,0}, aZ0 = {0,0,0,0}, aN0 = {0,0,0,0};
            f32x4 aR1 = {0,0,0,0}, aZ1 = {0,0,0,0}, aN1 = {0,0,0,0};
#pragma unroll
            for (int fi = 0; fi < 4; ++fi) {
                aR0 = __builtin_amdgcn_mfma_f32_16x16x32_f16(ap[fi], wxf[0][0][fi], aR0, 0, 0, 0);
                aZ0 = __builtin_amdgcn_mfma_f32_16x16x32_f16(ap[fi], wxf[1][0][fi], aZ0, 0, 0, 0);
                aN0 = __builtin_amdgcn_mfma_f32_16x16x32_f16(ap[fi], wxf[2][0][fi], aN0, 0, 0, 0);
                aR1 = __builtin_amdgcn_mfma_f32_16x16x32_f16(ap[fi], wxf[0][1][fi], aR1, 0, 0, 0);
                aZ1 = __builtin_amdgcn_mfma_f32_16x16x32_f16(ap[fi], wxf[1][1][fi], aZ1, 0, 0, 0);
                aN1 = __builtin_amdgcn_mfma_f32_16x16x32_f16(ap[fi], wxf[2][1][fi], aN1, 0, 0, 0);
            }
#pragma unroll
            for (int rb = 0; rb < 4; ++rb) {  // rb = batch (C/D reg)
                f16x4 p0 = {(_Float16)aR0[rb], (_Float16)aZ0[rb], (_Float16)aN0[rb], (_Float16)0.0f};
                f16x4 p1 = {(_Float16)aR1[rb], (_Float16)aZ1[rb], (_Float16)aN1[rb], (_Float16)0.0f};
                *(f16x4*)&ring[slot * RS + (rb * 128 + c0) * 4] = p0;
                *(f16x4*)&ring[slot * RS + (rb * 128 + c1) * 4] = p1;
            }
        };

        __syncthreads();      // #1: mu/dt/wxl/V4-zero visible
        {   // preamble: granule 0; barrier between stage & MMA (R6 NaN lesson)
            float4 px, pm;
            prodLoad(0, px, pm);
            prodStage(0, px, pm);
            barrier_lds_only();   // #2
            prodMMA(0);
            barrier_lds_only();   // #3: granule 0 visible
        }

        const int prow = (lm >> 2) * VR + quad * 8;  // dieted projection A-read
        float4 px, pm;
        for (int t = 0; t < 120; ++t) {
            const int gp = (t >> 2) + 1, ph = t & 3;
            if (ph == 0)      { if (gp < 30) prodLoad(gp, px, pm); }
            else if (ph == 1) { if (gp < 30) prodStage(gp, px, pm); }
            else if (ph == 2) { if (gp < 30) prodMMA(gp); }

            if (t >= 96) {  // projection: rep_t = decayed h = V4[t&1]
                f16x8 af[4];
#pragma unroll
                for (int fi = 0; fi < 4; ++fi)
                    af[fi] = *(const f16x8*)&V4[t & 1][prow + fi * 32];
                f32x4 aP = {bpv, 0, 0, 0};
#pragma unroll
                for (int fi = 0; fi < 4; ++fi)
                    aP = __builtin_amdgcn_mfma_f32_16x16x32_f16(af[fi], wPf[fi], aP, 0, 0, 0);
                out[((size_t)(b0 + quad) * 24 + (t - 96)) * 64 + pn] = aP[0];
            }
            barrier_lds_only();
        }
    } else {
        // ===================== CONSUMER WAVES (0..3) =====================
        const int c0 = 32 * w + lm, c1 = c0 + 16;

        // h-part B-frags (W_ih cols 64..191; +W_hh folded for r,z): 32 frags
        f16x8 wR[2][4], wZ[2][4], wN[2][4], wG[2][4];
        float S_[2], bh_[2], bR_[2], bZ_[2], bN_[2], bG_[2];
#pragma unroll
        for (int j = 0; j < 2; ++j) {
            const int c = j ? c1 : c0;
#pragma unroll
            for (int fi = 0; fi < 4; ++fi) {
                const int k0 = fi * 32 + quad * 8;
                wR[j][fi] = cvt8s(ld8(W_ih + c * 256 + 64 + k0),
                                  ld8(W_hh + c * 128 + k0));
                wZ[j][fi] = cvt8s(ld8(W_ih + (128 + c) * 256 + 64 + k0),
                                  ld8(W_hh + (128 + c) * 128 + k0));
                wN[j][fi] = cvt8(ld8(W_ih + (256 + c) * 256 + 64 + k0));
                wG[j][fi] = cvt8(ld8(W_hh + (256 + c) * 128 + k0));
            }
            float s = 0.0f;
            const float4* wh4 = (const float4*)(Wh_dec + c * 64);
#pragma unroll
            for (int i = 0; i < 16; ++i) { float4 u = wh4[i]; s += u.x + u.y + u.z + u.w; }
            S_[j]  = s;                       // dt @ Wh_dec.T = dt * rowsum
            bh_[j] = bh_dec[c];
            bR_[j] = b_ih[c] + b_hh[c];
            bZ_[j] = b_ih[128 + c] + b_hh[128 + c];
            bN_[j] = b_ih[256 + c];
            bG_[j] = b_hh[256 + c];
        }

        __syncthreads();      // #1
        barrier_lds_only();   // #2
        barrier_lds_only();   // #3

        const f32x4 ZV = {0.0f, 0.0f, 0.0f, 0.0f};
        const int vrow = (lm >> 2) * VR + quad * 8;  // dieted A-read (row lm>>2)
        float h0 = 0.0f, h1 = 0.0f;
        for (int t = 0; t < 120; ++t) {
            const _Float16* Vp = V4[t & 1];
            const int sb = (t & 7) * RS + quad * 512;  // [slot][b=quad][...]
            const f16x4 g0 = *(const f16x4*)&ring[sb + c0 * 4];
            const f16x4 g1 = *(const f16x4*)&ring[sb + c1 * 4];
            f16x8 af[4];
#pragma unroll
            for (int fi = 0; fi < 4; ++fi)
                af[fi] = *(const f16x8*)&Vp[vrow + fi * 32];

            // gh for t+1, off the gate chain
            const int tn = (t < 119) ? t + 1 : 119;
            const float dn = dt_lds[tn * 4 + quad];
            const float ghd0 = expnr_fast(dn * S_[0] + bh_[0]);
            const float ghd1 = expnr_fast(dn * S_[1] + bh_[1]);

            f32x4 aR0 = __builtin_amdgcn_mfma_f32_16x16x32_f16(af[0], wR[0][0], ZV, 0, 0, 0);
            f32x4 aZ0 = __builtin_amdgcn_mfma_f32_16x16x32_f16(af[0], wZ[0][0], ZV, 0, 0, 0);
            f32x4 aN0 = __builtin_amdgcn_mfma_f32_16x16x32_f16(af[0], wN[0][0], ZV, 0, 0, 0);
            f32x4 aG0 = __builtin_amdgcn_mfma_f32_16x16x32_f16(af[0], wG[0][0], ZV, 0, 0, 0);
            f32x4 aR1 = __builtin_amdgcn_mfma_f32_16x16x32_f16(af[0], wR[1][0], ZV, 0, 0, 0);
            f32x4 aZ1 = __builtin_amdgcn_mfma_f32_16x16x32_f16(af[0], wZ[1][0], ZV, 0, 0, 0);
            f32x4 aN1 = __builtin_amdgcn_mfma_f32_16x16x32_f16(af[0], wN[1][0], ZV, 0, 0, 0);
            f32x4 aG1 = __builtin_amdgcn_mfma_f32_16x16x32_f16(af[0], wG[1][0], ZV, 0, 0, 0);
#pragma unroll
            for (int fi = 1; fi < 4; ++fi) {
                aR0 = __builtin_amdgcn_mfma_f32_16x16x32_f16(af[fi], wR[0][fi], aR0, 0, 0, 0);
                aZ0 = __builtin_amdgcn_mfma_f32_16x16x32_f16(af[fi], wZ[0][fi], aZ0, 0, 0, 0);
                aN0 = __builtin_amdgcn_mfma_f32_16x16x32_f16(af[fi], wN[0][fi], aN0, 0, 0, 0);
                aG0 = __builtin_amdgcn_mfma_f32_16x16x32_f16(af[fi], wG[0][fi], aG0, 0, 0, 0);
                aR1 = __builtin_amdgcn_mfma_f32_16x16x32_f16(af[fi], wR[1][fi], aR1, 0, 0, 0);
                aZ1 = __builtin_amdgcn_mfma_f32_16x16x32_f16(af[fi], wZ[1][fi], aZ1, 0, 0, 0);
                aN1 = __builtin_amdgcn_mfma_f32_16x16x32_f16(af[fi], wN[1][fi], aN1, 0, 0, 0);
                aG1 = __builtin_amdgcn_mfma_f32_16x16x32_f16(af[fi], wG[1][fi], aG1, 0, 0, 0);
            }

            // gate triples (C/D reg 0: row 4*quad -> batch quad)
            const float rg0 = sig_fast(aR0[0] + ((float)g0[0] + bR_[0]));
            const float zg0 = sig_fast(aZ0[0] + ((float)g0[1] + bZ_[0]));
            const float ng0 = tanh_fast(aN0[0] + ((float)g0[2] + bN_[0]) + rg0 * (aG0[0] + bG_[0]));
            h0 = (zg0 * (h0 - ng0) + ng0) * ghd0;  // decayed h = rep_{t+1}
            const float rg1 = sig_fast(aR1[0] + ((float)g1[0] + bR_[1]));
            const float zg1 = sig_fast(aZ1[0] + ((float)g1[1] + bZ_[1]));
            const float ng1 = tanh_fast(aN1[0] + ((float)g1[2] + bN_[1]) + rg1 * (aG1[0] + bG_[1]));
            h1 = (zg1 * (h1 - ng1) + ng1) * ghd1;
            if (t < 119) {
                _Float16* Vn = V4[(t & 1) ^ 1];
                Vn[quad * VR + c0] = (_Float16)h0;
                Vn[quad * VR + c1] = (_Float16)h1;
            }
            barrier_lds_only();
        }
    }
}

extern "C" void kernel_launch(void* const* d_in, const int* in_sizes, int n_in,
                              void* d_out, int out_size, void* d_ws, size_t ws_size,
                              hipStream_t stream) {
    const float* tp_pred = (const float*)d_in[0];
    const float* X       = (const float*)d_in[1];
    const float* tp_true = (const float*)d_in[2];
    const float* mask    = (const float*)d_in[3];
    const float* Wh_dec  = (const float*)d_in[4];
    const float* bh_dec  = (const float*)d_in[5];
    const float* Wx_dec  = (const float*)d_in[6];
    const float* bx_dec  = (const float*)d_in[7];
    const float* W_ih    = (const float*)d_in[8];
    const float* W_hh    = (const float*)d_in[9];
    const float* b_ih    = (const float*)d_in[10];
    const float* b_hh    = (const float*)d_in[11];
    const float* Wp      = (const float*)d_in[12];
    const float* bp      = (const float*)d_in[13];

    grud_kernel<<<dim3(256), dim3(512), 0, stream>>>(
        tp_pred, X, tp_true, mask, Wh_dec, bh_dec, Wx_dec, bx_dec,
        W_ih, W_hh, b_ih, b_hh, Wp, bp, (float*)d_out);
}